// Round 8
// baseline (138.586 us; speedup 1.0000x reference)
//
#include <hip/hip_runtime.h>
#include <hip/hip_bf16.h>

#define B 8
#define T 2048
#define C 96
#define NH 3
#define HD 32
#define FFD 2048
#define HALF_W 32
#define BT (B*T)

typedef __hip_bfloat16 bf16;
typedef __attribute__((ext_vector_type(8))) short short8;
typedef __attribute__((ext_vector_type(4))) short short4v;
typedef __attribute__((ext_vector_type(16))) float floatx16;

__device__ __forceinline__ short f2bs(float v){
    __hip_bfloat16 h = __float2bfloat16(v);
    return *reinterpret_cast<short*>(&h);
}
__device__ __forceinline__ float bs2f(short s){
    unsigned u = ((unsigned)(unsigned short)s) << 16;
    return __uint_as_float(u);
}
__device__ __forceinline__ short8 ld_b64x2(const short* p){
    short4v a = *(const short4v*)p;
    short4v b = *(const short4v*)(p + 4);
    short8 v;
    v[0]=a[0]; v[1]=a[1]; v[2]=a[2]; v[3]=a[3];
    v[4]=b[0]; v[5]=b[1]; v[6]=b[2]; v[7]=b[3];
    return v;
}
// build an MFMA weight fragment directly from f32 row-major weights (L2-hot)
__device__ __forceinline__ short8 wfrag_f32(const float* wrow){
    float4 a = *(const float4*)(wrow);
    float4 b = *(const float4*)(wrow + 4);
    short8 v;
    v[0]=f2bs(a.x); v[1]=f2bs(a.y); v[2]=f2bs(a.z); v[3]=f2bs(a.w);
    v[4]=f2bs(b.x); v[5]=f2bs(b.y); v[6]=f2bs(b.z); v[7]=f2bs(b.w);
    return v;
}
__device__ __forceinline__ int4 exch_pair(int a0,int a1,int b0,int b1,int hq){
    int ra0=__shfl_xor(a0,32), ra1=__shfl_xor(a1,32);
    int rb0=__shfl_xor(b0,32), rb1=__shfl_xor(b1,32);
    int4 s;
    s.x = hq ? rb0 : a0;
    s.y = hq ? rb1 : a1;
    s.z = hq ? b0  : ra0;
    s.w = hq ? b1  : ra1;
    return s;
}
// pack acc(+bias) to bf16 and cross-hq exchange into two A/B-operand short8 fragments
__device__ __forceinline__ void proj_pack(const floatx16& acc, const float* bias32, int hq,
                                          short8& f0, short8& f1){
    int pkq[4][2];
    #pragma unroll
    for(int q = 0; q < 4; ++q){
        float4 bv = *(const float4*)(bias32 + 8*q + 4*hq);
        short4v t;
        t[0]=f2bs(acc[4*q+0]+bv.x); t[1]=f2bs(acc[4*q+1]+bv.y);
        t[2]=f2bs(acc[4*q+2]+bv.z); t[3]=f2bs(acc[4*q+3]+bv.w);
        int2 u = *(int2*)&t; pkq[q][0]=u.x; pkq[q][1]=u.y;
    }
    int4 r0 = exch_pair(pkq[0][0],pkq[0][1],pkq[1][0],pkq[1][1],hq);
    int4 r1 = exch_pair(pkq[2][0],pkq[2][1],pkq[3][0],pkq[3][1],hq);
    f0 = *(short8*)&r0; f1 = *(short8*)&r1;
}

// ---------------- K1: QKV + banded attention + outproj + residual + LN1 -------------
// 512 blocks x 384 thr (6 waves). batch = bid&7 (one batch per XCD).
// QKV/outproj weight fragments converted on-the-fly from f32 (L2-hot, 2x float4+cvt).
// ALSO converts a 768-element slice of the FF weights (w1s/w2s fragment-major bf16)
// per block -> cvtw dispatch eliminated; ff_kernel consumes via stream order.
// grp0 (waves 0-2): K proj + Q + attn + outproj + LN1; grp1 (waves 3-5): V proj.
__global__ __launch_bounds__(384, 4) void attn_kernel(
    const float* __restrict__ x,
    const float* __restrict__ wq, const float* __restrict__ wo,
    const float* __restrict__ w1f, const float* __restrict__ w2f,
    const float* __restrict__ b_qkv, const float* __restrict__ b_out,
    const float* __restrict__ g1, const float* __restrict__ bb1,
    bf16* __restrict__ w1s, bf16* __restrict__ w2s,
    bf16* __restrict__ h1b){
    // LDS map (bytes):
    //  [0,19200):      XS bf16[96 tok][100 ch]  ->  PTS short[3][3200]
    //  [19200,38400):  VTS short[3][3200]
    //  [38400,44800):  CTX short[32*100]
    //  [44800,45952):  LSS f32[96] + RED1 f32[2][96]
    __shared__ __align__(16) char smem[45952];
    short* XS   = (short*)smem;
    short* PTS  = (short*)smem;
    short* VTS  = (short*)(smem + 19200);
    short* CTX  = (short*)(smem + 38400);
    float* LSS  = (float*)(smem + 44800);
    float* RED1 = (float*)(smem + 45184);

    const int tid = threadIdx.x;
    const int u = tid >> 6, lane = tid & 63;
    const int lm = lane & 31, hq = lane >> 5;
    const int grp = u / 3, h = u % 3;
    const int b  = blockIdx.x & 7;       // XCD-aware: batch == XCD
    const int tt = blockIdx.x >> 3;
    const int t0 = tt * 32;
    const float* xb = x + (size_t)b*C*T;

    // ---- FF weight conversion slice (2 elems/thread), overlapped with x staging
    {
        const int base = blockIdx.x * 768;
        #pragma unroll
        for(int t2 = 0; t2 < 2; ++t2){
            int j = base + tid + t2*384;
            if(j < 196608){
                int e = j&7, ln = (j>>3)&63, r = j>>9;
                int ks = r%6, J = r/6;
                int row = J*32 + (ln&31);
                int k = ks*16 + (ln>>5)*8 + e;
                w1s[j] = __float2bfloat16(w1f[row*96 + k]);
            } else {
                int jj = j - 196608;
                int e = jj&7, ln = (jj>>3)&63, r = jj>>9;
                int ct = r%3; r /= 3;
                int g = r%2; int J = r/2;
                int c = ct*32 + (ln&31);
                int k = J*32 + g*16 + (ln>>5)*8 + e;
                w2s[jj] = __float2bfloat16(w2f[c*FFD + k]);
            }
        }
    }

    // ---- stage x halo [t0-32, t0+64) as bf16, token-major [96][100]
    int tg0 = t0 - 32;
    if(tg0 >= 0 && t0 + 64 <= T){
        for(int e = tid; e < 96*24; e += 384){
            int c = e / 24, t4 = e % 24;
            float4 v = *(const float4*)(xb + (size_t)c*T + tg0 + t4*4);
            XS[(t4*4+0)*100 + c] = f2bs(v.x);
            XS[(t4*4+1)*100 + c] = f2bs(v.y);
            XS[(t4*4+2)*100 + c] = f2bs(v.z);
            XS[(t4*4+3)*100 + c] = f2bs(v.w);
        }
    } else {
        for(int e = tid; e < 96*96; e += 384){
            int c = e / 96, j = e % 96;
            int t = tg0 + j; t = t < 0 ? 0 : (t > T-1 ? T-1 : t);
            XS[j*100 + c] = f2bs(xb[(size_t)c*T + t]);
        }
    }
    __syncthreads();                                   // b1: XS ready

    short8 wof[6];
    if(u < 3){
        #pragma unroll
        for(int ks = 0; ks < 6; ++ks)
            wof[ks] = wfrag_f32(wo + (size_t)(u*32 + lm)*96 + ks*16 + hq*8);
    }

    // ---- QKV projection (weights converted inline from f32)
    short8 kf[3][2], qf0, qf1;
    if(grp == 0){
        short8 kwf[6];
        #pragma unroll
        for(int ks = 0; ks < 6; ++ks)
            kwf[ks] = wfrag_f32(wq + (size_t)((3+h)*32 + lm)*96 + ks*16 + hq*8);
        #pragma unroll
        for(int tau = 0; tau < 3; ++tau){
            short8 bfr[6];
            #pragma unroll
            for(int ks = 0; ks < 6; ++ks)
                bfr[ks] = *(const short8*)(XS + (tau*32+lm)*100 + ks*16 + hq*8);
            floatx16 acc;
            #pragma unroll
            for(int r = 0; r < 16; ++r) acc[r] = 0.f;
            #pragma unroll
            for(int ks = 0; ks < 6; ++ks)
                acc = __builtin_amdgcn_mfma_f32_32x32x16_bf16(kwf[ks], bfr[ks], acc, 0,0,0);
            proj_pack(acc, b_qkv + (3+h)*32, hq, kf[tau][0], kf[tau][1]);
            if(tau == 1){
                floatx16 qa;
                #pragma unroll
                for(int r = 0; r < 16; ++r) qa[r] = 0.f;
                #pragma unroll
                for(int ks = 0; ks < 6; ++ks){
                    short8 qwf = wfrag_f32(wq + (size_t)(h*32 + lm)*96 + ks*16 + hq*8);
                    qa = __builtin_amdgcn_mfma_f32_32x32x16_bf16(qwf, bfr[ks], qa, 0,0,0);
                }
                proj_pack(qa, b_qkv + h*32, hq, qf0, qf1);
            }
        }
    } else {
        short8 vwf[6];
        #pragma unroll
        for(int ks = 0; ks < 6; ++ks)
            vwf[ks] = wfrag_f32(wq + (size_t)((6+h)*32 + lm)*96 + ks*16 + hq*8);
        #pragma unroll
        for(int tau = 0; tau < 3; ++tau){
            short8 bfr[6];
            #pragma unroll
            for(int ks = 0; ks < 6; ++ks)
                bfr[ks] = *(const short8*)(XS + (tau*32+lm)*100 + ks*16 + hq*8);
            floatx16 acc;
            #pragma unroll
            for(int r = 0; r < 16; ++r) acc[r] = 0.f;
            #pragma unroll
            for(int ks = 0; ks < 6; ++ks)
                acc = __builtin_amdgcn_mfma_f32_32x32x16_bf16(vwf[ks], bfr[ks], acc, 0,0,0);
            #pragma unroll
            for(int q = 0; q < 4; ++q){
                float4 bv = *(const float4*)(b_qkv + (6+h)*32 + 8*q + 4*hq);
                float bva[4] = {bv.x, bv.y, bv.z, bv.w};
                #pragma unroll
                for(int r = 0; r < 4; ++r)
                    VTS[h*3200 + (8*q + 4*hq + r)*100 + tau*32 + lm] = f2bs(acc[4*q+r] + bva[r]);
            }
        }
    }
    __syncthreads();                                   // b2: XS dead; VTS ready

    // ---- attention (grp0; wave h = head h)
    if(grp == 0){
        floatx16 S[3];
        #pragma unroll
        for(int sub = 0; sub < 3; ++sub){
            floatx16 z;
            #pragma unroll
            for(int r = 0; r < 16; ++r) z[r] = 0.f;
            z = __builtin_amdgcn_mfma_f32_32x32x16_bf16(kf[sub][0], qf0, z, 0,0,0);
            z = __builtin_amdgcn_mfma_f32_32x32x16_bf16(kf[sub][1], qf1, z, 0,0,0);
            S[sub] = z;
        }
        const float scale = 0.17677669529663687f;
        float part = 0.f;
        #pragma unroll
        for(int sub = 0; sub < 3; ++sub){
            #pragma unroll
            for(int r = 0; r < 16; ++r){
                int key_local = sub*32 + (r&3) + 8*(r>>2) + 4*hq;
                int s_glob = t0 - 32 + key_local;
                int rel = key_local - lm;
                bool ok = (rel >= 0) && (rel <= 64) && (s_glob >= 0) && (s_glob < T);
                float pe = ok ? __expf(S[sub][r]*scale) : 0.f;
                S[sub][r] = pe;
                part += pe;
            }
        }
        float ltot = part + __shfl_xor(part, 32);
        if(hq == 0) LSS[h*32 + lm] = ltot;
        #pragma unroll
        for(int sub = 0; sub < 3; ++sub){
            #pragma unroll
            for(int q4 = 0; q4 < 4; ++q4){
                int kbase = sub*32 + 8*q4 + 4*hq;
                short4v pk4;
                pk4[0] = f2bs(S[sub][4*q4+0]);
                pk4[1] = f2bs(S[sub][4*q4+1]);
                pk4[2] = f2bs(S[sub][4*q4+2]);
                pk4[3] = f2bs(S[sub][4*q4+3]);
                *(short4v*)(PTS + h*3200 + lm*100 + kbase) = pk4;
            }
        }
        floatx16 O;
        #pragma unroll
        for(int r = 0; r < 16; ++r) O[r] = 0.f;
        #pragma unroll
        for(int ks = 0; ks < 6; ++ks){
            short8 pa = ld_b64x2(PTS + h*3200 + lm*100 + ks*16 + hq*8);
            short8 vf = ld_b64x2(VTS + h*3200 + lm*100 + ks*16 + hq*8);
            O = __builtin_amdgcn_mfma_f32_32x32x16_bf16(pa, vf, O, 0,0,0);
        }
        #pragma unroll
        for(int r = 0; r < 16; ++r){
            int qr = (r&3) + 8*(r>>2) + 4*hq;
            float linv = 1.f / LSS[h*32 + qr];
            CTX[qr*100 + h*32 + lm] = f2bs(O[r]*linv);
        }
    }
    __syncthreads();                                   // b3: CTX ready

    // ---- outproj + residual + LN1 (waves 0..2, ct=u) -> global h1b
    float vals[16];
    if(u < 3){
        short8 cbfr[6];
        #pragma unroll
        for(int ks = 0; ks < 6; ++ks)
            cbfr[ks] = ld_b64x2(CTX + lm*100 + ks*16 + hq*8);
        floatx16 pacc;
        #pragma unroll
        for(int r = 0; r < 16; ++r) pacc[r] = 0.f;
        #pragma unroll
        for(int ks = 0; ks < 6; ++ks)
            pacc = __builtin_amdgcn_mfma_f32_32x32x16_bf16(wof[ks], cbfr[ks], pacc, 0,0,0);
        float p1 = 0.f, p2 = 0.f;
        #pragma unroll
        for(int q = 0; q < 4; ++q){
            int c = u*32 + 8*q + 4*hq;
            float4 bv = *(const float4*)(b_out + c);
            float bva[4] = {bv.x, bv.y, bv.z, bv.w};
            #pragma unroll
            for(int r = 0; r < 4; ++r){
                float xv = xb[(size_t)(c + r)*T + t0 + lm];
                float v = pacc[4*q+r] + bva[r] + xv;
                vals[4*q+r] = v;
                p1 += v; p2 += v*v;
            }
        }
        p1 += __shfl_xor(p1, 32);
        p2 += __shfl_xor(p2, 32);
        if(hq == 0){ RED1[u*32 + lm] = p1; RED1[96 + u*32 + lm] = p2; }
    }
    __syncthreads();                                   // b4
    if(u < 3){
        float s  = RED1[lm] + RED1[32 + lm] + RED1[64 + lm];
        float s2 = RED1[96 + lm] + RED1[128 + lm] + RED1[160 + lm];
        float mu = s * (1.0f/96.0f);
        float rstd = rsqrtf(s2*(1.0f/96.0f) - mu*mu + 1e-5f);
        int row = b*T + t0 + lm;
        #pragma unroll
        for(int q = 0; q < 4; ++q){
            int c = u*32 + 8*q + 4*hq;
            float4 gv = *(const float4*)(g1 + c);
            float4 bv = *(const float4*)(bb1 + c);
            float ga[4] = {gv.x, gv.y, gv.z, gv.w};
            float ba[4] = {bv.x, bv.y, bv.z, bv.w};
            short4v pkv;
            #pragma unroll
            for(int r = 0; r < 4; ++r)
                pkv[r] = f2bs((vals[4*q+r] - mu)*rstd*ga[r] + ba[r]);
            *(short4v*)((short*)h1b + (size_t)row*96 + c) = pkv;
        }
    }
}

// ---------------- K2: FF, 64-token tiles (mt=2), 256 blocks x 4 waves ---------------
// w1 prefetch double-buffered across J-iters; w2 loaded at iteration top (covered by
// FF1 chain). Plain-LDS staged partial reduce -> 55 KB LDS -> 2 blocks/CU.
__global__ __launch_bounds__(256, 2) void ff_kernel(
    const bf16* __restrict__ h1b,
    const bf16* __restrict__ w1s, const float* __restrict__ b1,
    const bf16* __restrict__ w2s, const float* __restrict__ b2,
    const float* __restrict__ g2, const float* __restrict__ bt2,
    const float* __restrict__ gf, const float* __restrict__ btf,
    float* __restrict__ out){
    // LDS: REDP f32[12][1088] [0,52224)  (ZT f32[96*68]=26112 aliased at [0,26112))
    //      RED1 f32[2][2][96] [52224,53760) ; RED2 f32[2][2][96] [53760,55296)
    __shared__ __align__(16) char smem[55296];
    float* REDP = (float*)smem;
    float* ZT   = (float*)smem;
    float* RED1 = (float*)(smem + 52224);
    float* RED2 = (float*)(smem + 53760);

    const int tid = threadIdx.x;
    const int w4 = tid >> 6, lane = tid & 63;
    const int lm = lane & 31, hq = lane >> 5;
    const int r0 = blockIdx.x * 64;
    const short* h1p = (const short*)h1b;

    short8 hf[2][6];
    #pragma unroll
    for(int mt = 0; mt < 2; ++mt)
        #pragma unroll
        for(int ks = 0; ks < 6; ++ks)
            hf[mt][ks] = *(const short8*)(h1p + (size_t)(r0 + mt*32 + lm)*96 + ks*16 + hq*8);

    floatx16 acc2[2][3];
    #pragma unroll
    for(int mt = 0; mt < 2; ++mt)
        #pragma unroll
        for(int i = 0; i < 3; ++i)
            #pragma unroll
            for(int r = 0; r < 16; ++r) acc2[mt][i][r] = 0.f;

    const short* w1b = (const short*)w1s + lane*8;
    const short* w2b = (const short*)w2s + lane*8;
    short8 cw1[6];
    #pragma unroll
    for(int ks = 0; ks < 6; ++ks)
        cw1[ks] = *(const short8*)(w1b + (size_t)(w4*6 + ks)*512);

    for(int it = 0; it < 16; ++it){
        const int J  = w4 + it*4;
        const int Jn = (it < 15) ? J + 4 : w4;
        short8 w2f[6];
        #pragma unroll
        for(int g = 0; g < 2; ++g)
            #pragma unroll
            for(int ct = 0; ct < 3; ++ct)
                w2f[g*3 + ct] = *(const short8*)(w2b + (size_t)((J*2 + g)*3 + ct)*512);
        short8 nw1[6];
        #pragma unroll
        for(int ks = 0; ks < 6; ++ks)
            nw1[ks] = *(const short8*)(w1b + (size_t)(Jn*6 + ks)*512);
        floatx16 a0, a1;
        #pragma unroll
        for(int r = 0; r < 16; ++r){ a0[r] = 0.f; a1[r] = 0.f; }
        #pragma unroll
        for(int ks = 0; ks < 6; ++ks){
            a0 = __builtin_amdgcn_mfma_f32_32x32x16_bf16(cw1[ks], hf[0][ks], a0, 0,0,0);
            a1 = __builtin_amdgcn_mfma_f32_32x32x16_bf16(cw1[ks], hf[1][ks], a1, 0,0,0);
        }
        int pk[2][4][2];
        #pragma unroll
        for(int q = 0; q < 4; ++q){
            float4 bv = *(const float4*)(b1 + J*32 + 8*q + 4*hq);
            float bva[4] = {bv.x, bv.y, bv.z, bv.w};
            short4v t0v, t1v;
            #pragma unroll
            for(int r = 0; r < 4; ++r){
                float v0 = a0[4*q+r] + bva[r];
                float v1 = a1[4*q+r] + bva[r];
                t0v[r] = f2bs(v0 > 0.f ? v0 : 0.f);
                t1v[r] = f2bs(v1 > 0.f ? v1 : 0.f);
            }
            int2 u0 = *(int2*)&t0v; int2 u1 = *(int2*)&t1v;
            pk[0][q][0] = u0.x; pk[0][q][1] = u0.y;
            pk[1][q][0] = u1.x; pk[1][q][1] = u1.y;
        }
        #pragma unroll
        for(int g = 0; g < 2; ++g){
            #pragma unroll
            for(int mt = 0; mt < 2; ++mt){
                int4 sfi = exch_pair(pk[mt][2*g][0], pk[mt][2*g][1],
                                     pk[mt][2*g+1][0], pk[mt][2*g+1][1], hq);
                short8 sf = *(short8*)&sfi;
                #pragma unroll
                for(int ct = 0; ct < 3; ++ct)
                    acc2[mt][ct] = __builtin_amdgcn_mfma_f32_32x32x16_bf16(
                                       w2f[g*3+ct], sf, acc2[mt][ct], 0,0,0);
            }
        }
        #pragma unroll
        for(int ks = 0; ks < 6; ++ks) cw1[ks] = nw1[ks];
    }

    // ---- staged partial reduce: REDP pass per mt, consumed by waves 0..2 (ct=w4)
    float fv[2][16];
    float e1m[2], e2m[2];
    #pragma unroll
    for(int mt = 0; mt < 2; ++mt){
        #pragma unroll
        for(int ct = 0; ct < 3; ++ct)
            #pragma unroll
            for(int q = 0; q < 4; ++q)
                #pragma unroll
                for(int r = 0; r < 4; ++r)
                    REDP[(w4*3 + ct)*1088 + lane*17 + 4*q + r] = acc2[mt][ct][4*q+r];
        __syncthreads();                               // dump complete
        if(w4 < 3){
            float e1 = 0.f, e2 = 0.f;
            #pragma unroll
            for(int q = 0; q < 4; ++q){
                int cb = w4*32 + 8*q + 4*hq;
                float4 bv = *(const float4*)(b2 + cb);
                float bva[4] = {bv.x, bv.y, bv.z, bv.w};
                short4v hv = *(const short4v*)(h1p + (size_t)(r0 + mt*32 + lm)*96 + cb);
                #pragma unroll
                for(int r = 0; r < 4; ++r){
                    float v = REDP[(0*3 + w4)*1088 + lane*17 + 4*q + r]
                            + REDP[(1*3 + w4)*1088 + lane*17 + 4*q + r]
                            + REDP[(2*3 + w4)*1088 + lane*17 + 4*q + r]
                            + REDP[(3*3 + w4)*1088 + lane*17 + 4*q + r]
                            + bva[r] + bs2f(hv[r]);
                    fv[mt][4*q+r] = v;
                    e1 += v; e2 += v*v;
                }
            }
            e1m[mt] = e1 + __shfl_xor(e1, 32);
            e2m[mt] = e2 + __shfl_xor(e2, 32);
        }
        __syncthreads();                               // reads done; REDP reusable
    }
    if(w4 < 3 && hq == 0){
        #pragma unroll
        for(int mt = 0; mt < 2; ++mt){
            RED1[mt*192 + w4*32 + lm] = e1m[mt];
            RED1[mt*192 + 96 + w4*32 + lm] = e2m[mt];
        }
    }
    __syncthreads();                                   // RED1 ready
    float f1m[2], f2m[2];
    if(w4 < 3){
        #pragma unroll
        for(int mt = 0; mt < 2; ++mt){
            float s  = RED1[mt*192 + lm] + RED1[mt*192 + 32 + lm] + RED1[mt*192 + 64 + lm];
            float s2 = RED1[mt*192 + 96 + lm] + RED1[mt*192 + 128 + lm] + RED1[mt*192 + 160 + lm];
            float mu = s * (1.0f/96.0f);
            float rstd = rsqrtf(s2*(1.0f/96.0f) - mu*mu + 1e-5f);
            float f1 = 0.f, f2 = 0.f;
            #pragma unroll
            for(int q = 0; q < 4; ++q){
                int c = w4*32 + 8*q + 4*hq;
                float4 gv = *(const float4*)(g2 + c);
                float4 bv = *(const float4*)(bt2 + c);
                float ga[4] = {gv.x, gv.y, gv.z, gv.w};
                float ba[4] = {bv.x, bv.y, bv.z, bv.w};
                #pragma unroll
                for(int r = 0; r < 4; ++r){
                    float y = (fv[mt][4*q+r] - mu)*rstd*ga[r] + ba[r];
                    fv[mt][4*q+r] = y;
                    f1 += y; f2 += y*y;
                }
            }
            f1m[mt] = f1 + __shfl_xor(f1, 32);
            f2m[mt] = f2 + __shfl_xor(f2, 32);
        }
        if(hq == 0){
            #pragma unroll
            for(int mt = 0; mt < 2; ++mt){
                RED2[mt*192 + w4*32 + lm] = f1m[mt];
                RED2[mt*192 + 96 + w4*32 + lm] = f2m[mt];
            }
        }
    }
    __syncthreads();                                   // RED2 ready; REDP dead
    if(w4 < 3){
        #pragma unroll
        for(int mt = 0; mt < 2; ++mt){
            float s  = RED2[mt*192 + lm] + RED2[mt*192 + 32 + lm] + RED2[mt*192 + 64 + lm];
            float s2 = RED2[mt*192 + 96 + lm] + RED2[mt*192 + 128 + lm] + RED2[mt*192 + 160 + lm];
            float mu = s * (1.0f/96.0f);
            float rstd = rsqrtf(s2*(1.0f/96.0f) - mu*mu + 1e-5f);
            #pragma unroll
            for(int q = 0; q < 4; ++q){
                int c = w4*32 + 8*q + 4*hq;
                float4 gv = *(const float4*)(gf + c);
                float4 bv = *(const float4*)(btf + c);
                float ga[4] = {gv.x, gv.y, gv.z, gv.w};
                float ba[4] = {bv.x, bv.y, bv.z, bv.w};
                #pragma unroll
                for(int r = 0; r < 4; ++r)
                    ZT[(c + r)*68 + mt*32 + lm] = (fv[mt][4*q+r] - mu)*rstd*ga[r] + ba[r];
            }
        }
    }
    __syncthreads();                                   // ZT ready
    const int bb = r0 / T, t0g = r0 % T;
    float* ob = out + (size_t)bb*C*T + t0g;
    for(int e = tid; e < 96*16; e += 256){
        int c = e >> 4, tg = e & 15;
        *(float4*)(ob + (size_t)c*T + tg*4) = *(const float4*)(ZT + c*68 + tg*4);
    }
}

extern "C" void kernel_launch(void* const* d_in, const int* in_sizes, int n_in,
                              void* d_out, int out_size, void* d_ws, size_t ws_size,
                              hipStream_t stream) {
    const float* x     = (const float*)d_in[0];
    const float* w_qkv = (const float*)d_in[1];
    const float* b_qkv = (const float*)d_in[2];
    const float* w_out = (const float*)d_in[3];
    const float* b_out = (const float*)d_in[4];
    const float* ln1_g = (const float*)d_in[5];
    const float* ln1_b = (const float*)d_in[6];
    const float* w_ff1 = (const float*)d_in[7];
    const float* b_ff1 = (const float*)d_in[8];
    const float* w_ff2 = (const float*)d_in[9];
    const float* b_ff2 = (const float*)d_in[10];
    const float* ln2_g = (const float*)d_in[11];
    const float* ln2_b = (const float*)d_in[12];
    const float* lnf_g = (const float*)d_in[13];
    const float* lnf_b = (const float*)d_in[14];
    float* out = (float*)d_out;

    // ws: w1s bf16[196608] + w2s bf16[196608] (786 KB) + h1b bf16[16384][96] (3.1 MB)
    char* wsb = (char*)d_ws;
    bf16* w1s = (bf16*)wsb;
    bf16* w2s = (bf16*)(wsb + 393216);
    bf16* h1b = (bf16*)(wsb + 786432);

    attn_kernel<<<512, 384, 0, stream>>>(x, w_qkv, w_out, w_ff1, w_ff2,
                                         b_qkv, b_out, ln1_g, ln1_b,
                                         w1s, w2s, h1b);
    ff_kernel  <<<BT/64, 256, 0, stream>>>(h1b, w1s, b_ff1, w2s, b_ff2,
                                           ln2_g, ln2_b, lnf_g, lnf_b, out);
}

// Round 9
// 124.193 us; speedup vs baseline: 1.1159x; 1.1159x over previous
//
#include <hip/hip_runtime.h>
#include <hip/hip_bf16.h>

#define B 8
#define T 2048
#define C 96
#define NH 3
#define HD 32
#define FFD 2048
#define HALF_W 32
#define BT (B*T)

typedef __hip_bfloat16 bf16;
typedef __attribute__((ext_vector_type(8))) short short8;
typedef __attribute__((ext_vector_type(4))) short short4v;
typedef __attribute__((ext_vector_type(16))) float floatx16;

__device__ __forceinline__ short f2bs(float v){
    __hip_bfloat16 h = __float2bfloat16(v);
    return *reinterpret_cast<short*>(&h);
}
__device__ __forceinline__ float bs2f(short s){
    unsigned u = ((unsigned)(unsigned short)s) << 16;
    return __uint_as_float(u);
}
__device__ __forceinline__ short8 ld_b64x2(const short* p){
    short4v a = *(const short4v*)p;
    short4v b = *(const short4v*)(p + 4);
    short8 v;
    v[0]=a[0]; v[1]=a[1]; v[2]=a[2]; v[3]=a[3];
    v[4]=b[0]; v[5]=b[1]; v[6]=b[2]; v[7]=b[3];
    return v;
}
__device__ __forceinline__ int4 exch_pair(int a0,int a1,int b0,int b1,int hq){
    int ra0=__shfl_xor(a0,32), ra1=__shfl_xor(a1,32);
    int rb0=__shfl_xor(b0,32), rb1=__shfl_xor(b1,32);
    int4 s;
    s.x = hq ? rb0 : a0;
    s.y = hq ? rb1 : a1;
    s.z = hq ? b0  : ra0;
    s.w = hq ? b1  : ra1;
    return s;
}
// pack acc(+bias) to bf16 and cross-hq exchange into two A/B-operand short8 fragments
__device__ __forceinline__ void proj_pack(const floatx16& acc, const float* bias32, int hq,
                                          short8& f0, short8& f1){
    int pkq[4][2];
    #pragma unroll
    for(int q = 0; q < 4; ++q){
        float4 bv = *(const float4*)(bias32 + 8*q + 4*hq);
        short4v t;
        t[0]=f2bs(acc[4*q+0]+bv.x); t[1]=f2bs(acc[4*q+1]+bv.y);
        t[2]=f2bs(acc[4*q+2]+bv.z); t[3]=f2bs(acc[4*q+3]+bv.w);
        int2 u = *(int2*)&t; pkq[q][0]=u.x; pkq[q][1]=u.y;
    }
    int4 r0 = exch_pair(pkq[0][0],pkq[0][1],pkq[1][0],pkq[1][1],hq);
    int4 r1 = exch_pair(pkq[2][0],pkq[2][1],pkq[3][0],pkq[3][1],hq);
    f0 = *(short8*)&r0; f1 = *(short8*)&r1;
}

// ---------------- K0: convert weights to bf16 in FRAGMENT-MAJOR (swizzled) layout ----
__global__ void cvtw_kernel(const float* __restrict__ wq, const float* __restrict__ wo,
                            const float* __restrict__ w1, const float* __restrict__ w2,
                            bf16* __restrict__ dst){
    int i = blockIdx.x*256 + threadIdx.x;
    if(i < 27648){
        int e = i&7, lane = (i>>3)&63, r = i>>9;
        int ks = r%6, ot = r/6;
        int o = ot*32 + (lane&31);
        int k = ks*16 + (lane>>5)*8 + e;
        dst[i] = __float2bfloat16(wq[o*96 + k]);
    } else if(i < 36864){
        int j = i - 27648;
        int e = j&7, lane = (j>>3)&63, r = j>>9;
        int ks = r%6, ct = r/6;
        int c = ct*32 + (lane&31);
        int k = ks*16 + (lane>>5)*8 + e;
        dst[i] = __float2bfloat16(wo[c*96 + k]);
    } else if(i < 233472){
        int j = i - 36864;
        int e = j&7, lane = (j>>3)&63, r = j>>9;
        int ks = r%6; r /= 6;
        int w = r%4, jt = r/4;
        int row = jt*128 + w*32 + (lane&31);
        int k = ks*16 + (lane>>5)*8 + e;
        dst[i] = __float2bfloat16(w1[row*96 + k]);
    } else if(i < 430080){
        int j = i - 233472;
        int e = j&7, lane = (j>>3)&63, r = j>>9;
        int ct = r%3; r /= 3;
        int g = r%2; r /= 2;
        int w = r%4, jt = r/4;
        int c = ct*32 + (lane&31);
        int k = jt*128 + w*32 + g*16 + (lane>>5)*8 + e;
        dst[i] = __float2bfloat16(w2[c*FFD + k]);
    }
}

// ---------------- K1: FULLY-FUSED encoder layer, one block = 32 tokens ----------------
// 512 blocks x 192 threads (3 waves), 73 KB LDS (phase-aliased), 2 blocks/CU.
// Best-measured configuration of the session (R1: 125.0 us total, encoder ~49 us).
__global__ __launch_bounds__(192, 2) void encoder_kernel(
    const float* __restrict__ x,
    const bf16* __restrict__ wqs, const bf16* __restrict__ wos,
    const bf16* __restrict__ w1s, const bf16* __restrict__ w2s,
    const float* __restrict__ b_qkv, const float* __restrict__ b_out,
    const float* __restrict__ g1, const float* __restrict__ bb1,
    const float* __restrict__ b1, const float* __restrict__ b2,
    const float* __restrict__ g2, const float* __restrict__ bt2,
    const float* __restrict__ gf, const float* __restrict__ btf,
    float* __restrict__ out){
    // LDS region map (bytes), aliased by phase:
    //  A [0, 39936):  XS f32[96][104]  ->  PTS short[3][3200]  ->  REDP f32[9][1088]
    //  B [39936, 59136): VTS short[3][3200]  ->  ZT f32[96][36]
    //  C [59136, 65536): CTX short[32][100]
    //  D [65536, 71936): H1S short[32][100]
    //  E [71936, 73088): LSS f32[96] + RED1 f32[2][96]
    __shared__ __align__(16) char smem[73088];
    float* XS   = (float*)smem;
    short* PTS  = (short*)smem;
    float* REDP = (float*)smem;
    short* VTS  = (short*)(smem + 39936);
    float* ZT   = (float*)(smem + 39936);
    short* CTX  = (short*)(smem + 59136);
    short* H1S  = (short*)(smem + 65536);
    float* LSS  = (float*)(smem + 71936);
    float* RED1 = (float*)(smem + 72320);

    const int tid = threadIdx.x;
    const int w = tid / 64, lane = tid & 63;
    const int lm = lane & 31, hq = lane >> 5;
    const int b  = blockIdx.x >> 6;
    const int tt = blockIdx.x & 63;
    const int t0 = tt * 32;
    const float* xb = x + (size_t)b*C*T;

    // preload outproj weight fragments (ct = w)
    short8 wof[6];
    #pragma unroll
    for(int ks = 0; ks < 6; ++ks)
        wof[ks] = *(const short8*)((const short*)wos + (size_t)(w*6 + ks)*512 + lane*8);

    // ---- stage x halo [t0-32, t0+64) as f32 [96][104]
    int tg0 = t0 - 32;
    if(tg0 >= 0 && t0 + 64 <= T){
        for(int e = tid; e < 96*24; e += 192){
            int c = e / 24, q4 = e % 24;
            *(float4*)(XS + c*104 + q4*4) = *(const float4*)(xb + (size_t)c*T + tg0 + q4*4);
        }
    } else {
        for(int e = tid; e < 96*96; e += 192){
            int c = e / 96, j = e % 96;
            int t = tg0 + j; t = t < 0 ? 0 : (t > T-1 ? T-1 : t);
            XS[c*104 + j] = xb[(size_t)c*T + t];
        }
    }
    __syncthreads();                                   // b1: XS ready

    // ---- in-block QKV proj. wave w = head w. K/V for 3 tiles, Q for center.
    short8 kwf[6], vwf[6];
    #pragma unroll
    for(int ks = 0; ks < 6; ++ks){
        kwf[ks] = *(const short8*)((const short*)wqs + (size_t)((3+w)*6 + ks)*512 + lane*8);
        vwf[ks] = *(const short8*)((const short*)wqs + (size_t)((6+w)*6 + ks)*512 + lane*8);
    }
    short8 kf[3][2]; short8 qf0, qf1;
    #pragma unroll
    for(int tau = 0; tau < 3; ++tau){
        short8 bfr[6];
        #pragma unroll
        for(int ks = 0; ks < 6; ++ks){
            short8 vv;
            #pragma unroll
            for(int i = 0; i < 8; ++i)
                vv[i] = f2bs(XS[(ks*16 + hq*8 + i)*104 + tau*32 + lm]);
            bfr[ks] = vv;
        }
        floatx16 acc;
        #pragma unroll
        for(int r = 0; r < 16; ++r) acc[r] = 0.f;
        #pragma unroll
        for(int ks = 0; ks < 6; ++ks)
            acc = __builtin_amdgcn_mfma_f32_32x32x16_bf16(kwf[ks], bfr[ks], acc, 0,0,0);
        proj_pack(acc, b_qkv + (3+w)*32, hq, kf[tau][0], kf[tau][1]);
        #pragma unroll
        for(int r = 0; r < 16; ++r) acc[r] = 0.f;
        #pragma unroll
        for(int ks = 0; ks < 6; ++ks)
            acc = __builtin_amdgcn_mfma_f32_32x32x16_bf16(vwf[ks], bfr[ks], acc, 0,0,0);
        #pragma unroll
        for(int q = 0; q < 4; ++q){
            float4 bv = *(const float4*)(b_qkv + (6+w)*32 + 8*q + 4*hq);
            float bva[4] = {bv.x, bv.y, bv.z, bv.w};
            #pragma unroll
            for(int r = 0; r < 4; ++r)
                VTS[w*3200 + (8*q + 4*hq + r)*100 + tau*32 + lm] = f2bs(acc[4*q+r] + bva[r]);
        }
        if(tau == 1){
            floatx16 qa;
            #pragma unroll
            for(int r = 0; r < 16; ++r) qa[r] = 0.f;
            #pragma unroll
            for(int ks = 0; ks < 6; ++ks){
                short8 qwf = *(const short8*)((const short*)wqs + (size_t)(w*6 + ks)*512 + lane*8);
                qa = __builtin_amdgcn_mfma_f32_32x32x16_bf16(qwf, bfr[ks], qa, 0,0,0);
            }
            proj_pack(qa, b_qkv + w*32, hq, qf0, qf1);
        }
    }
    __syncthreads();                                   // b2: XS dead, PTS region free

    // ---- S phase (queries t0+lm, head w)
    floatx16 S[3];
    #pragma unroll
    for(int sub = 0; sub < 3; ++sub){
        floatx16 z;
        #pragma unroll
        for(int r = 0; r < 16; ++r) z[r] = 0.f;
        z = __builtin_amdgcn_mfma_f32_32x32x16_bf16(kf[sub][0], qf0, z, 0,0,0);
        z = __builtin_amdgcn_mfma_f32_32x32x16_bf16(kf[sub][1], qf1, z, 0,0,0);
        S[sub] = z;
    }
    const float scale = 0.17677669529663687f;
    float part = 0.f;
    #pragma unroll
    for(int sub = 0; sub < 3; ++sub){
        #pragma unroll
        for(int r = 0; r < 16; ++r){
            int key_local = sub*32 + (r&3) + 8*(r>>2) + 4*hq;
            int s_glob = t0 - 32 + key_local;
            int rel = key_local - lm;
            bool ok = (rel >= 0) && (rel <= 64) && (s_glob >= 0) && (s_glob < T);
            float p = ok ? __expf(S[sub][r]*scale) : 0.f;
            S[sub][r] = p;
            part += p;
        }
    }
    float ltot = part + __shfl_xor(part, 32);
    if(hq == 0) LSS[w*32 + lm] = ltot;
    #pragma unroll
    for(int sub = 0; sub < 3; ++sub){
        #pragma unroll
        for(int q4 = 0; q4 < 4; ++q4){
            int kbase = sub*32 + 8*q4 + 4*hq;
            short4v pk4;
            pk4[0] = f2bs(S[sub][4*q4+0]);
            pk4[1] = f2bs(S[sub][4*q4+1]);
            pk4[2] = f2bs(S[sub][4*q4+2]);
            pk4[3] = f2bs(S[sub][4*q4+3]);
            *(short4v*)(PTS + w*3200 + lm*100 + kbase) = pk4;
        }
    }
    // ---- PV (PTS/VTS are same-wave data; no barrier needed)
    floatx16 O;
    #pragma unroll
    for(int r = 0; r < 16; ++r) O[r] = 0.f;
    #pragma unroll
    for(int ks = 0; ks < 6; ++ks){
        short8 pa = ld_b64x2(PTS + w*3200 + lm*100 + ks*16 + hq*8);
        short8 vf = ld_b64x2(VTS + w*3200 + lm*100 + ks*16 + hq*8);
        O = __builtin_amdgcn_mfma_f32_32x32x16_bf16(pa, vf, O, 0,0,0);
    }
    #pragma unroll
    for(int r = 0; r < 16; ++r){
        int qr = (r&3) + 8*(r>>2) + 4*hq;
        float linv = 1.f / LSS[w*32 + qr];
        CTX[qr*100 + w*32 + lm] = f2bs(O[r]*linv);
    }
    __syncthreads();                                   // b3: CTX ready

    // ---- outproj + residual + LN1 (wave w = ct)
    short8 cbfr[6];
    #pragma unroll
    for(int ks = 0; ks < 6; ++ks)
        cbfr[ks] = ld_b64x2(CTX + lm*100 + ks*16 + hq*8);
    floatx16 pacc;
    #pragma unroll
    for(int r = 0; r < 16; ++r) pacc[r] = 0.f;
    #pragma unroll
    for(int ks = 0; ks < 6; ++ks)
        pacc = __builtin_amdgcn_mfma_f32_32x32x16_bf16(wof[ks], cbfr[ks], pacc, 0,0,0);
    float vals[16];
    float p1 = 0.f, p2 = 0.f;
    #pragma unroll
    for(int q = 0; q < 4; ++q){
        int c = w*32 + 8*q + 4*hq;
        float4 bv = *(const float4*)(b_out + c);
        float bva[4] = {bv.x, bv.y, bv.z, bv.w};
        #pragma unroll
        for(int r = 0; r < 4; ++r){
            float xv = xb[(size_t)(c + r)*T + t0 + lm];
            float v = pacc[4*q+r] + bva[r] + xv;
            vals[4*q+r] = v;
            p1 += v; p2 += v*v;
        }
    }
    p1 += __shfl_xor(p1, 32);
    p2 += __shfl_xor(p2, 32);
    if(hq == 0){ RED1[w*32 + lm] = p1; RED1[96 + w*32 + lm] = p2; }
    __syncthreads();                                   // b4
    {
        float s  = RED1[lm] + RED1[32 + lm] + RED1[64 + lm];
        float s2 = RED1[96 + lm] + RED1[128 + lm] + RED1[160 + lm];
        float mu = s * (1.0f/96.0f);
        float rstd = rsqrtf(s2*(1.0f/96.0f) - mu*mu + 1e-5f);
        #pragma unroll
        for(int q = 0; q < 4; ++q){
            int c = w*32 + 8*q + 4*hq;
            float4 gv = *(const float4*)(g1 + c);
            float4 bv = *(const float4*)(bb1 + c);
            float ga[4] = {gv.x, gv.y, gv.z, gv.w};
            float ba[4] = {bv.x, bv.y, bv.z, bv.w};
            short4v pkv;
            #pragma unroll
            for(int r = 0; r < 4; ++r)
                pkv[r] = f2bs((vals[4*q+r] - mu)*rstd*ga[r] + ba[r]);
            *(short4v*)(H1S + lm*100 + c) = pkv;
        }
    }
    __syncthreads();                                   // b5: H1S ready

    // ---- FF: wave w owns col-tiles J = w, w+3, ... (22/21/21)
    short8 hf[6];
    #pragma unroll
    for(int ks = 0; ks < 6; ++ks)
        hf[ks] = ld_b64x2(H1S + lm*100 + ks*16 + hq*8);
    floatx16 acc2[3];
    #pragma unroll
    for(int i = 0; i < 3; ++i)
        #pragma unroll
        for(int r = 0; r < 16; ++r) acc2[i][r] = 0.f;
    const short* w1b = (const short*)w1s + lane*8;
    const short* w2b = (const short*)w2s + lane*8;
    short8 cw1[6], cw2[6];
    #pragma unroll
    for(int ks = 0; ks < 6; ++ks)
        cw1[ks] = *(const short8*)(w1b + (size_t)(w*6 + ks)*512);
    #pragma unroll
    for(int g = 0; g < 2; ++g)
        #pragma unroll
        for(int ct = 0; ct < 3; ++ct)
            cw2[g*3 + ct] = *(const short8*)(w2b + (size_t)((w*2 + g)*3 + ct)*512);
    for(int J = w; J < 64; J += 3){
        int Jn = (J + 3 < 64) ? J + 3 : w;
        short8 nw1[6], nw2[6];
        #pragma unroll
        for(int ks = 0; ks < 6; ++ks)
            nw1[ks] = *(const short8*)(w1b + (size_t)(Jn*6 + ks)*512);
        #pragma unroll
        for(int g = 0; g < 2; ++g)
            #pragma unroll
            for(int ct = 0; ct < 3; ++ct)
                nw2[g*3 + ct] = *(const short8*)(w2b + (size_t)((Jn*2 + g)*3 + ct)*512);
        floatx16 a0;
        #pragma unroll
        for(int r = 0; r < 16; ++r) a0[r] = 0.f;
        #pragma unroll
        for(int ks = 0; ks < 6; ++ks)
            a0 = __builtin_amdgcn_mfma_f32_32x32x16_bf16(cw1[ks], hf[ks], a0, 0,0,0);
        int pk[4][2];
        #pragma unroll
        for(int q = 0; q < 4; ++q){
            float4 bv = *(const float4*)(b1 + J*32 + 8*q + 4*hq);
            float bva[4] = {bv.x, bv.y, bv.z, bv.w};
            short4v tv;
            #pragma unroll
            for(int r = 0; r < 4; ++r){
                float v0 = a0[4*q+r] + bva[r];
                tv[r] = f2bs(v0 > 0.f ? v0 : 0.f);
            }
            int2 u = *(int2*)&tv; pk[q][0] = u.x; pk[q][1] = u.y;
        }
        #pragma unroll
        for(int g = 0; g < 2; ++g){
            int4 sfi = exch_pair(pk[2*g][0], pk[2*g][1], pk[2*g+1][0], pk[2*g+1][1], hq);
            short8 sf = *(short8*)&sfi;
            #pragma unroll
            for(int ct = 0; ct < 3; ++ct)
                acc2[ct] = __builtin_amdgcn_mfma_f32_32x32x16_bf16(cw2[g*3+ct], sf, acc2[ct], 0,0,0);
        }
        #pragma unroll
        for(int ks = 0; ks < 6; ++ks) cw1[ks] = nw1[ks];
        #pragma unroll
        for(int i = 0; i < 6; ++i) cw2[i] = nw2[i];
    }
    #pragma unroll
    for(int ct = 0; ct < 3; ++ct)
        #pragma unroll
        for(int q = 0; q < 4; ++q)
            #pragma unroll
            for(int r = 0; r < 4; ++r)
                REDP[(w*3 + ct)*1088 + lane*17 + 4*q + r] = acc2[ct][4*q+r];
    __syncthreads();                                   // b6: partials ready

    // ---- FF2 reduce + residual + LN2 + LNf (wave w = ct)
    float fv[16];
    float e1 = 0.f, e2 = 0.f;
    #pragma unroll
    for(int q = 0; q < 4; ++q){
        int c = w*32 + 8*q + 4*hq;
        float4 bv = *(const float4*)(b2 + c);
        float bva[4] = {bv.x, bv.y, bv.z, bv.w};
        #pragma unroll
        for(int r = 0; r < 4; ++r){
            float v = REDP[(0 + w)*1088 + lane*17 + 4*q + r]
                    + REDP[(3 + w)*1088 + lane*17 + 4*q + r]
                    + REDP[(6 + w)*1088 + lane*17 + 4*q + r]
                    + bva[r] + bs2f(H1S[lm*100 + c + r]);
            fv[4*q+r] = v;
            e1 += v; e2 += v*v;
        }
    }
    e1 += __shfl_xor(e1, 32);
    e2 += __shfl_xor(e2, 32);
    if(hq == 0){ RED1[w*32 + lm] = e1; RED1[96 + w*32 + lm] = e2; }
    __syncthreads();                                   // b7
    float f1 = 0.f, f2 = 0.f;
    {
        float s  = RED1[lm] + RED1[32 + lm] + RED1[64 + lm];
        float s2 = RED1[96 + lm] + RED1[128 + lm] + RED1[160 + lm];
        float mu = s * (1.0f/96.0f);
        float rstd = rsqrtf(s2*(1.0f/96.0f) - mu*mu + 1e-5f);
        #pragma unroll
        for(int q = 0; q < 4; ++q){
            int c = w*32 + 8*q + 4*hq;
            float4 gv = *(const float4*)(g2 + c);
            float4 bv = *(const float4*)(bt2 + c);
            float ga[4] = {gv.x, gv.y, gv.z, gv.w};
            float ba[4] = {bv.x, bv.y, bv.z, bv.w};
            #pragma unroll
            for(int r = 0; r < 4; ++r){
                float y = (fv[4*q+r] - mu)*rstd*ga[r] + ba[r];
                fv[4*q+r] = y;
                f1 += y; f2 += y*y;
            }
        }
    }
    f1 += __shfl_xor(f1, 32);
    f2 += __shfl_xor(f2, 32);
    __syncthreads();                                   // b8: round-1 reads complete
    if(hq == 0){ RED1[w*32 + lm] = f1; RED1[96 + w*32 + lm] = f2; }
    __syncthreads();                                   // b9
    {
        float s  = RED1[lm] + RED1[32 + lm] + RED1[64 + lm];
        float s2 = RED1[96 + lm] + RED1[128 + lm] + RED1[160 + lm];
        float mu = s * (1.0f/96.0f);
        float rstd = rsqrtf(s2*(1.0f/96.0f) - mu*mu + 1e-5f);
        #pragma unroll
        for(int q = 0; q < 4; ++q){
            int c = w*32 + 8*q + 4*hq;
            float4 gv = *(const float4*)(gf + c);
            float4 bv = *(const float4*)(btf + c);
            float ga[4] = {gv.x, gv.y, gv.z, gv.w};
            float ba[4] = {bv.x, bv.y, bv.z, bv.w};
            #pragma unroll
            for(int r = 0; r < 4; ++r)
                ZT[(c + r)*36 + lm] = (fv[4*q+r] - mu)*rstd*ga[r] + ba[r];
        }
    }
    __syncthreads();                                   // b10: ZT ready
    float* ob = out + (size_t)b*C*T + t0;
    for(int e = tid; e < 96*8; e += 192){
        int c = e >> 3, qq = e & 7;
        *(float4*)(ob + (size_t)c*T + qq*4) = *(const float4*)(ZT + c*36 + qq*4);
    }
}

extern "C" void kernel_launch(void* const* d_in, const int* in_sizes, int n_in,
                              void* d_out, int out_size, void* d_ws, size_t ws_size,
                              hipStream_t stream) {
    const float* x     = (const float*)d_in[0];
    const float* w_qkv = (const float*)d_in[1];
    const float* b_qkv = (const float*)d_in[2];
    const float* w_out = (const float*)d_in[3];
    const float* b_out = (const float*)d_in[4];
    const float* ln1_g = (const float*)d_in[5];
    const float* ln1_b = (const float*)d_in[6];
    const float* w_ff1 = (const float*)d_in[7];
    const float* b_ff1 = (const float*)d_in[8];
    const float* w_ff2 = (const float*)d_in[9];
    const float* b_ff2 = (const float*)d_in[10];
    const float* ln2_g = (const float*)d_in[11];
    const float* ln2_b = (const float*)d_in[12];
    const float* lnf_g = (const float*)d_in[13];
    const float* lnf_b = (const float*)d_in[14];
    float* out = (float*)d_out;

    // ws: only bf16 fragment-major weights (860 KB)
    bf16* wts = (bf16*)d_ws;
    bf16* wqs = wts;
    bf16* wos = wts + 27648;
    bf16* w1s = wts + 36864;
    bf16* w2s = wts + 233472;

    cvtw_kernel   <<<1680, 256, 0, stream>>>(w_qkv, w_out, w_ff1, w_ff2, wts);
    encoder_kernel<<<B*(T/32), 192, 0, stream>>>(x, wqs, wos, w1s, w2s,
                                                 b_qkv, b_out, ln1_g, ln1_b,
                                                 b_ff1, b_ff2, ln2_g, ln2_b,
                                                 lnf_g, lnf_b, out);
}

// Round 10
// 123.712 us; speedup vs baseline: 1.1202x; 1.0039x over previous
//
#include <hip/hip_runtime.h>
#include <hip/hip_bf16.h>

#define B 8
#define T 2048
#define C 96
#define NH 3
#define HD 32
#define FFD 2048
#define HALF_W 32
#define BT (B*T)

typedef __hip_bfloat16 bf16;
typedef __attribute__((ext_vector_type(8))) short short8;
typedef __attribute__((ext_vector_type(4))) short short4v;
typedef __attribute__((ext_vector_type(16))) float floatx16;

__device__ __forceinline__ short f2bs(float v){
    __hip_bfloat16 h = __float2bfloat16(v);
    return *reinterpret_cast<short*>(&h);
}
__device__ __forceinline__ float bs2f(short s){
    unsigned u = ((unsigned)(unsigned short)s) << 16;
    return __uint_as_float(u);
}
__device__ __forceinline__ short8 ld_b64x2(const short* p){
    short4v a = *(const short4v*)p;
    short4v b = *(const short4v*)(p + 4);
    short8 v;
    v[0]=a[0]; v[1]=a[1]; v[2]=a[2]; v[3]=a[3];
    v[4]=b[0]; v[5]=b[1]; v[6]=b[2]; v[7]=b[3];
    return v;
}
__device__ __forceinline__ int4 exch_pair(int a0,int a1,int b0,int b1,int hq){
    int ra0=__shfl_xor(a0,32), ra1=__shfl_xor(a1,32);
    int rb0=__shfl_xor(b0,32), rb1=__shfl_xor(b1,32);
    int4 s;
    s.x = hq ? rb0 : a0;
    s.y = hq ? rb1 : a1;
    s.z = hq ? b0  : ra0;
    s.w = hq ? b1  : ra1;
    return s;
}
// pack acc(+bias) to bf16 and cross-hq exchange into two A/B-operand short8 fragments
__device__ __forceinline__ void proj_pack(const floatx16& acc, const float* bias32, int hq,
                                          short8& f0, short8& f1){
    int pkq[4][2];
    #pragma unroll
    for(int q = 0; q < 4; ++q){
        float4 bv = *(const float4*)(bias32 + 8*q + 4*hq);
        short4v t;
        t[0]=f2bs(acc[4*q+0]+bv.x); t[1]=f2bs(acc[4*q+1]+bv.y);
        t[2]=f2bs(acc[4*q+2]+bv.z); t[3]=f2bs(acc[4*q+3]+bv.w);
        int2 u = *(int2*)&t; pkq[q][0]=u.x; pkq[q][1]=u.y;
    }
    int4 r0 = exch_pair(pkq[0][0],pkq[0][1],pkq[1][0],pkq[1][1],hq);
    int4 r1 = exch_pair(pkq[2][0],pkq[2][1],pkq[3][0],pkq[3][1],hq);
    f0 = *(short8*)&r0; f1 = *(short8*)&r1;
}

// ---------------- K0: convert weights to bf16 in FRAGMENT-MAJOR (swizzled) layout ----
__global__ void cvtw_kernel(const float* __restrict__ wq, const float* __restrict__ wo,
                            const float* __restrict__ w1, const float* __restrict__ w2,
                            bf16* __restrict__ dst){
    int i = blockIdx.x*256 + threadIdx.x;
    if(i < 27648){
        int e = i&7, lane = (i>>3)&63, r = i>>9;
        int ks = r%6, ot = r/6;
        int o = ot*32 + (lane&31);
        int k = ks*16 + (lane>>5)*8 + e;
        dst[i] = __float2bfloat16(wq[o*96 + k]);
    } else if(i < 36864){
        int j = i - 27648;
        int e = j&7, lane = (j>>3)&63, r = j>>9;
        int ks = r%6, ct = r/6;
        int c = ct*32 + (lane&31);
        int k = ks*16 + (lane>>5)*8 + e;
        dst[i] = __float2bfloat16(wo[c*96 + k]);
    } else if(i < 233472){
        int j = i - 36864;
        int e = j&7, lane = (j>>3)&63, r = j>>9;
        int ks = r%6; r /= 6;
        int w = r%4, jt = r/4;
        int row = jt*128 + w*32 + (lane&31);
        int k = ks*16 + (lane>>5)*8 + e;
        dst[i] = __float2bfloat16(w1[row*96 + k]);
    } else if(i < 430080){
        int j = i - 233472;
        int e = j&7, lane = (j>>3)&63, r = j>>9;
        int ct = r%3; r /= 3;
        int g = r%2; r /= 2;
        int w = r%4, jt = r/4;
        int c = ct*32 + (lane&31);
        int k = jt*128 + w*32 + g*16 + (lane>>5)*8 + e;
        dst[i] = __float2bfloat16(w2[c*FFD + k]);
    }
}

// ---------------- K1: FULLY-FUSED encoder layer, one block = 32 tokens ----------------
// 512 blocks x 192 threads (3 waves), 73 KB LDS (phase-aliased), 2 blocks/CU.
// R9 base (124.2 us) + FF loop processes 2 J-tiles/iter: two independent 6-deep FF1
// MFMA chains (a0/a1) -> halves the dominant dependent-latency stall. Single-variable
// change; block count / LDS / barriers / per-J math order unchanged.
__global__ __launch_bounds__(192, 2) void encoder_kernel(
    const float* __restrict__ x,
    const bf16* __restrict__ wqs, const bf16* __restrict__ wos,
    const bf16* __restrict__ w1s, const bf16* __restrict__ w2s,
    const float* __restrict__ b_qkv, const float* __restrict__ b_out,
    const float* __restrict__ g1, const float* __restrict__ bb1,
    const float* __restrict__ b1, const float* __restrict__ b2,
    const float* __restrict__ g2, const float* __restrict__ bt2,
    const float* __restrict__ gf, const float* __restrict__ btf,
    float* __restrict__ out){
    // LDS region map (bytes), aliased by phase:
    //  A [0, 39936):  XS f32[96][104]  ->  PTS short[3][3200]  ->  REDP f32[9][1088]
    //  B [39936, 59136): VTS short[3][3200]  ->  ZT f32[96][36]
    //  C [59136, 65536): CTX short[32][100]
    //  D [65536, 71936): H1S short[32][100]
    //  E [71936, 73088): LSS f32[96] + RED1 f32[2][96]
    __shared__ __align__(16) char smem[73088];
    float* XS   = (float*)smem;
    short* PTS  = (short*)smem;
    float* REDP = (float*)smem;
    short* VTS  = (short*)(smem + 39936);
    float* ZT   = (float*)(smem + 39936);
    short* CTX  = (short*)(smem + 59136);
    short* H1S  = (short*)(smem + 65536);
    float* LSS  = (float*)(smem + 71936);
    float* RED1 = (float*)(smem + 72320);

    const int tid = threadIdx.x;
    const int w = tid / 64, lane = tid & 63;
    const int lm = lane & 31, hq = lane >> 5;
    const int b  = blockIdx.x >> 6;
    const int tt = blockIdx.x & 63;
    const int t0 = tt * 32;
    const float* xb = x + (size_t)b*C*T;

    // preload outproj weight fragments (ct = w)
    short8 wof[6];
    #pragma unroll
    for(int ks = 0; ks < 6; ++ks)
        wof[ks] = *(const short8*)((const short*)wos + (size_t)(w*6 + ks)*512 + lane*8);

    // ---- stage x halo [t0-32, t0+64) as f32 [96][104]
    int tg0 = t0 - 32;
    if(tg0 >= 0 && t0 + 64 <= T){
        for(int e = tid; e < 96*24; e += 192){
            int c = e / 24, q4 = e % 24;
            *(float4*)(XS + c*104 + q4*4) = *(const float4*)(xb + (size_t)c*T + tg0 + q4*4);
        }
    } else {
        for(int e = tid; e < 96*96; e += 192){
            int c = e / 96, j = e % 96;
            int t = tg0 + j; t = t < 0 ? 0 : (t > T-1 ? T-1 : t);
            XS[c*104 + j] = xb[(size_t)c*T + t];
        }
    }
    __syncthreads();                                   // b1: XS ready

    // ---- in-block QKV proj. wave w = head w. K/V for 3 tiles, Q for center.
    short8 kwf[6], vwf[6];
    #pragma unroll
    for(int ks = 0; ks < 6; ++ks){
        kwf[ks] = *(const short8*)((const short*)wqs + (size_t)((3+w)*6 + ks)*512 + lane*8);
        vwf[ks] = *(const short8*)((const short*)wqs + (size_t)((6+w)*6 + ks)*512 + lane*8);
    }
    short8 kf[3][2]; short8 qf0, qf1;
    #pragma unroll
    for(int tau = 0; tau < 3; ++tau){
        short8 bfr[6];
        #pragma unroll
        for(int ks = 0; ks < 6; ++ks){
            short8 vv;
            #pragma unroll
            for(int i = 0; i < 8; ++i)
                vv[i] = f2bs(XS[(ks*16 + hq*8 + i)*104 + tau*32 + lm]);
            bfr[ks] = vv;
        }
        floatx16 acc;
        #pragma unroll
        for(int r = 0; r < 16; ++r) acc[r] = 0.f;
        #pragma unroll
        for(int ks = 0; ks < 6; ++ks)
            acc = __builtin_amdgcn_mfma_f32_32x32x16_bf16(kwf[ks], bfr[ks], acc, 0,0,0);
        proj_pack(acc, b_qkv + (3+w)*32, hq, kf[tau][0], kf[tau][1]);
        #pragma unroll
        for(int r = 0; r < 16; ++r) acc[r] = 0.f;
        #pragma unroll
        for(int ks = 0; ks < 6; ++ks)
            acc = __builtin_amdgcn_mfma_f32_32x32x16_bf16(vwf[ks], bfr[ks], acc, 0,0,0);
        #pragma unroll
        for(int q = 0; q < 4; ++q){
            float4 bv = *(const float4*)(b_qkv + (6+w)*32 + 8*q + 4*hq);
            float bva[4] = {bv.x, bv.y, bv.z, bv.w};
            #pragma unroll
            for(int r = 0; r < 4; ++r)
                VTS[w*3200 + (8*q + 4*hq + r)*100 + tau*32 + lm] = f2bs(acc[4*q+r] + bva[r]);
        }
        if(tau == 1){
            floatx16 qa;
            #pragma unroll
            for(int r = 0; r < 16; ++r) qa[r] = 0.f;
            #pragma unroll
            for(int ks = 0; ks < 6; ++ks){
                short8 qwf = *(const short8*)((const short*)wqs + (size_t)(w*6 + ks)*512 + lane*8);
                qa = __builtin_amdgcn_mfma_f32_32x32x16_bf16(qwf, bfr[ks], qa, 0,0,0);
            }
            proj_pack(qa, b_qkv + w*32, hq, qf0, qf1);
        }
    }
    __syncthreads();                                   // b2: XS dead, PTS region free

    // ---- S phase (queries t0+lm, head w)
    floatx16 S[3];
    #pragma unroll
    for(int sub = 0; sub < 3; ++sub){
        floatx16 z;
        #pragma unroll
        for(int r = 0; r < 16; ++r) z[r] = 0.f;
        z = __builtin_amdgcn_mfma_f32_32x32x16_bf16(kf[sub][0], qf0, z, 0,0,0);
        z = __builtin_amdgcn_mfma_f32_32x32x16_bf16(kf[sub][1], qf1, z, 0,0,0);
        S[sub] = z;
    }
    const float scale = 0.17677669529663687f;
    float part = 0.f;
    #pragma unroll
    for(int sub = 0; sub < 3; ++sub){
        #pragma unroll
        for(int r = 0; r < 16; ++r){
            int key_local = sub*32 + (r&3) + 8*(r>>2) + 4*hq;
            int s_glob = t0 - 32 + key_local;
            int rel = key_local - lm;
            bool ok = (rel >= 0) && (rel <= 64) && (s_glob >= 0) && (s_glob < T);
            float p = ok ? __expf(S[sub][r]*scale) : 0.f;
            S[sub][r] = p;
            part += p;
        }
    }
    float ltot = part + __shfl_xor(part, 32);
    if(hq == 0) LSS[w*32 + lm] = ltot;
    #pragma unroll
    for(int sub = 0; sub < 3; ++sub){
        #pragma unroll
        for(int q4 = 0; q4 < 4; ++q4){
            int kbase = sub*32 + 8*q4 + 4*hq;
            short4v pk4;
            pk4[0] = f2bs(S[sub][4*q4+0]);
            pk4[1] = f2bs(S[sub][4*q4+1]);
            pk4[2] = f2bs(S[sub][4*q4+2]);
            pk4[3] = f2bs(S[sub][4*q4+3]);
            *(short4v*)(PTS + w*3200 + lm*100 + kbase) = pk4;
        }
    }
    // ---- PV (PTS/VTS are same-wave data; no barrier needed)
    floatx16 O;
    #pragma unroll
    for(int r = 0; r < 16; ++r) O[r] = 0.f;
    #pragma unroll
    for(int ks = 0; ks < 6; ++ks){
        short8 pa = ld_b64x2(PTS + w*3200 + lm*100 + ks*16 + hq*8);
        short8 vf = ld_b64x2(VTS + w*3200 + lm*100 + ks*16 + hq*8);
        O = __builtin_amdgcn_mfma_f32_32x32x16_bf16(pa, vf, O, 0,0,0);
    }
    #pragma unroll
    for(int r = 0; r < 16; ++r){
        int qr = (r&3) + 8*(r>>2) + 4*hq;
        float linv = 1.f / LSS[w*32 + qr];
        CTX[qr*100 + w*32 + lm] = f2bs(O[r]*linv);
    }
    __syncthreads();                                   // b3: CTX ready

    // ---- outproj + residual + LN1 (wave w = ct)
    short8 cbfr[6];
    #pragma unroll
    for(int ks = 0; ks < 6; ++ks)
        cbfr[ks] = ld_b64x2(CTX + lm*100 + ks*16 + hq*8);
    floatx16 pacc;
    #pragma unroll
    for(int r = 0; r < 16; ++r) pacc[r] = 0.f;
    #pragma unroll
    for(int ks = 0; ks < 6; ++ks)
        pacc = __builtin_amdgcn_mfma_f32_32x32x16_bf16(wof[ks], cbfr[ks], pacc, 0,0,0);
    float vals[16];
    float p1 = 0.f, p2 = 0.f;
    #pragma unroll
    for(int q = 0; q < 4; ++q){
        int c = w*32 + 8*q + 4*hq;
        float4 bv = *(const float4*)(b_out + c);
        float bva[4] = {bv.x, bv.y, bv.z, bv.w};
        #pragma unroll
        for(int r = 0; r < 4; ++r){
            float xv = xb[(size_t)(c + r)*T + t0 + lm];
            float v = pacc[4*q+r] + bva[r] + xv;
            vals[4*q+r] = v;
            p1 += v; p2 += v*v;
        }
    }
    p1 += __shfl_xor(p1, 32);
    p2 += __shfl_xor(p2, 32);
    if(hq == 0){ RED1[w*32 + lm] = p1; RED1[96 + w*32 + lm] = p2; }
    __syncthreads();                                   // b4
    {
        float s  = RED1[lm] + RED1[32 + lm] + RED1[64 + lm];
        float s2 = RED1[96 + lm] + RED1[128 + lm] + RED1[160 + lm];
        float mu = s * (1.0f/96.0f);
        float rstd = rsqrtf(s2*(1.0f/96.0f) - mu*mu + 1e-5f);
        #pragma unroll
        for(int q = 0; q < 4; ++q){
            int c = w*32 + 8*q + 4*hq;
            float4 gv = *(const float4*)(g1 + c);
            float4 bv = *(const float4*)(bb1 + c);
            float ga[4] = {gv.x, gv.y, gv.z, gv.w};
            float ba[4] = {bv.x, bv.y, bv.z, bv.w};
            short4v pkv;
            #pragma unroll
            for(int r = 0; r < 4; ++r)
                pkv[r] = f2bs((vals[4*q+r] - mu)*rstd*ga[r] + ba[r]);
            *(short4v*)(H1S + lm*100 + c) = pkv;
        }
    }
    __syncthreads();                                   // b5: H1S ready

    // ---- FF: wave w owns J = w+3k; TWO J-tiles per iteration (independent FF1 chains)
    short8 hf[6];
    #pragma unroll
    for(int ks = 0; ks < 6; ++ks)
        hf[ks] = ld_b64x2(H1S + lm*100 + ks*16 + hq*8);
    floatx16 acc2[3];
    #pragma unroll
    for(int i = 0; i < 3; ++i)
        #pragma unroll
        for(int r = 0; r < 16; ++r) acc2[i][r] = 0.f;
    const short* w1b = (const short*)w1s + lane*8;
    const short* w2b = (const short*)w2s + lane*8;
    const int nJ = (w == 0) ? 22 : 21;
    const int npair = nJ >> 1;                         // 11 / 10 / 10
    short8 cw1a[6], cw1b[6];
    #pragma unroll
    for(int ks = 0; ks < 6; ++ks){
        cw1a[ks] = *(const short8*)(w1b + (size_t)(w*6 + ks)*512);
        cw1b[ks] = *(const short8*)(w1b + (size_t)((w+3)*6 + ks)*512);
    }
    for(int i = 0; i < npair; ++i){
        const int Ja = w + 3*(2*i), Jb = Ja + 3;
        // w2 fragments for this pair (consumed after the FF1 chains)
        short8 w2fa[6], w2fb[6];
        #pragma unroll
        for(int g = 0; g < 2; ++g)
            #pragma unroll
            for(int ct = 0; ct < 3; ++ct){
                w2fa[g*3 + ct] = *(const short8*)(w2b + (size_t)((Ja*2 + g)*3 + ct)*512);
                w2fb[g*3 + ct] = *(const short8*)(w2b + (size_t)((Jb*2 + g)*3 + ct)*512);
            }
        // FF1: two INDEPENDENT 6-deep chains (2-way MFMA ILP)
        floatx16 a0, a1;
        #pragma unroll
        for(int r = 0; r < 16; ++r){ a0[r] = 0.f; a1[r] = 0.f; }
        #pragma unroll
        for(int ks = 0; ks < 6; ++ks){
            a0 = __builtin_amdgcn_mfma_f32_32x32x16_bf16(cw1a[ks], hf[ks], a0, 0,0,0);
            a1 = __builtin_amdgcn_mfma_f32_32x32x16_bf16(cw1b[ks], hf[ks], a1, 0,0,0);
        }
        // pack both streams (bias + ReLU + bf16)
        int pkA[4][2], pkB[4][2];
        #pragma unroll
        for(int q = 0; q < 4; ++q){
            float4 bva4 = *(const float4*)(b1 + Ja*32 + 8*q + 4*hq);
            float4 bvb4 = *(const float4*)(b1 + Jb*32 + 8*q + 4*hq);
            float ba_[4] = {bva4.x, bva4.y, bva4.z, bva4.w};
            float bb_[4] = {bvb4.x, bvb4.y, bvb4.z, bvb4.w};
            short4v ta, tb;
            #pragma unroll
            for(int r = 0; r < 4; ++r){
                float v0 = a0[4*q+r] + ba_[r];
                float v1 = a1[4*q+r] + bb_[r];
                ta[r] = f2bs(v0 > 0.f ? v0 : 0.f);
                tb[r] = f2bs(v1 > 0.f ? v1 : 0.f);
            }
            int2 ua = *(int2*)&ta; int2 ub = *(int2*)&tb;
            pkA[q][0] = ua.x; pkA[q][1] = ua.y;
            pkB[q][0] = ub.x; pkB[q][1] = ub.y;
        }
        // prefetch next pair's w1 HERE (a0/a1/cw1 now dead -> bounded VGPR peak);
        // load latency covered by FF2 + next-iter w2 loads
        int JnA = Ja, JnB = Jb;
        if(i + 1 < npair){ JnA = Ja + 6; JnB = Jb + 6; }
        else if(nJ & 1){ JnA = w + 3*(2*npair); JnB = JnA; }
        short8 nw1a[6], nw1b[6];
        #pragma unroll
        for(int ks = 0; ks < 6; ++ks){
            nw1a[ks] = *(const short8*)(w1b + (size_t)(JnA*6 + ks)*512);
            nw1b[ks] = *(const short8*)(w1b + (size_t)(JnB*6 + ks)*512);
        }
        // FF2: 4 MFMAs per ct per iter, 3 interleaved acc2 chains
        #pragma unroll
        for(int g = 0; g < 2; ++g){
            int4 sAi = exch_pair(pkA[2*g][0], pkA[2*g][1], pkA[2*g+1][0], pkA[2*g+1][1], hq);
            int4 sBi = exch_pair(pkB[2*g][0], pkB[2*g][1], pkB[2*g+1][0], pkB[2*g+1][1], hq);
            short8 sfA = *(short8*)&sAi;
            short8 sfB = *(short8*)&sBi;
            #pragma unroll
            for(int ct = 0; ct < 3; ++ct){
                acc2[ct] = __builtin_amdgcn_mfma_f32_32x32x16_bf16(w2fa[g*3+ct], sfA, acc2[ct], 0,0,0);
                acc2[ct] = __builtin_amdgcn_mfma_f32_32x32x16_bf16(w2fb[g*3+ct], sfB, acc2[ct], 0,0,0);
            }
        }
        #pragma unroll
        for(int ks = 0; ks < 6; ++ks){ cw1a[ks] = nw1a[ks]; cw1b[ks] = nw1b[ks]; }
    }
    if(nJ & 1){                                        // odd tail (waves 1,2)
        const int J = w + 3*(2*npair);
        short8 w2f[6];
        #pragma unroll
        for(int g = 0; g < 2; ++g)
            #pragma unroll
            for(int ct = 0; ct < 3; ++ct)
                w2f[g*3 + ct] = *(const short8*)(w2b + (size_t)((J*2 + g)*3 + ct)*512);
        floatx16 a0;
        #pragma unroll
        for(int r = 0; r < 16; ++r) a0[r] = 0.f;
        #pragma unroll
        for(int ks = 0; ks < 6; ++ks)
            a0 = __builtin_amdgcn_mfma_f32_32x32x16_bf16(cw1a[ks], hf[ks], a0, 0,0,0);
        int pk[4][2];
        #pragma unroll
        for(int q = 0; q < 4; ++q){
            float4 bv = *(const float4*)(b1 + J*32 + 8*q + 4*hq);
            float bva[4] = {bv.x, bv.y, bv.z, bv.w};
            short4v tv;
            #pragma unroll
            for(int r = 0; r < 4; ++r){
                float v0 = a0[4*q+r] + bva[r];
                tv[r] = f2bs(v0 > 0.f ? v0 : 0.f);
            }
            int2 u = *(int2*)&tv; pk[q][0] = u.x; pk[q][1] = u.y;
        }
        #pragma unroll
        for(int g = 0; g < 2; ++g){
            int4 sfi = exch_pair(pk[2*g][0], pk[2*g][1], pk[2*g+1][0], pk[2*g+1][1], hq);
            short8 sf = *(short8*)&sfi;
            #pragma unroll
            for(int ct = 0; ct < 3; ++ct)
                acc2[ct] = __builtin_amdgcn_mfma_f32_32x32x16_bf16(w2f[g*3+ct], sf, acc2[ct], 0,0,0);
        }
    }
    #pragma unroll
    for(int ct = 0; ct < 3; ++ct)
        #pragma unroll
        for(int q = 0; q < 4; ++q)
            #pragma unroll
            for(int r = 0; r < 4; ++r)
                REDP[(w*3 + ct)*1088 + lane*17 + 4*q + r] = acc2[ct][4*q+r];
    __syncthreads();                                   // b6: partials ready

    // ---- FF2 reduce + residual + LN2 + LNf (wave w = ct)
    float fv[16];
    float e1 = 0.f, e2 = 0.f;
    #pragma unroll
    for(int q = 0; q < 4; ++q){
        int c = w*32 + 8*q + 4*hq;
        float4 bv = *(const float4*)(b2 + c);
        float bva[4] = {bv.x, bv.y, bv.z, bv.w};
        #pragma unroll
        for(int r = 0; r < 4; ++r){
            float v = REDP[(0 + w)*1088 + lane*17 + 4*q + r]
                    + REDP[(3 + w)*1088 + lane*17 + 4*q + r]
                    + REDP[(6 + w)*1088 + lane*17 + 4*q + r]
                    + bva[r] + bs2f(H1S[lm*100 + c + r]);
            fv[4*q+r] = v;
            e1 += v; e2 += v*v;
        }
    }
    e1 += __shfl_xor(e1, 32);
    e2 += __shfl_xor(e2, 32);
    if(hq == 0){ RED1[w*32 + lm] = e1; RED1[96 + w*32 + lm] = e2; }
    __syncthreads();                                   // b7
    float f1 = 0.f, f2 = 0.f;
    {
        float s  = RED1[lm] + RED1[32 + lm] + RED1[64 + lm];
        float s2 = RED1[96 + lm] + RED1[128 + lm] + RED1[160 + lm];
        float mu = s * (1.0f/96.0f);
        float rstd = rsqrtf(s2*(1.0f/96.0f) - mu*mu + 1e-5f);
        #pragma unroll
        for(int q = 0; q < 4; ++q){
            int c = w*32 + 8*q + 4*hq;
            float4 gv = *(const float4*)(g2 + c);
            float4 bv = *(const float4*)(bt2 + c);
            float ga[4] = {gv.x, gv.y, gv.z, gv.w};
            float ba[4] = {bv.x, bv.y, bv.z, bv.w};
            #pragma unroll
            for(int r = 0; r < 4; ++r){
                float y = (fv[4*q+r] - mu)*rstd*ga[r] + ba[r];
                fv[4*q+r] = y;
                f1 += y; f2 += y*y;
            }
        }
    }
    f1 += __shfl_xor(f1, 32);
    f2 += __shfl_xor(f2, 32);
    __syncthreads();                                   // b8: round-1 reads complete
    if(hq == 0){ RED1[w*32 + lm] = f1; RED1[96 + w*32 + lm] = f2; }
    __syncthreads();                                   // b9
    {
        float s  = RED1[lm] + RED1[32 + lm] + RED1[64 + lm];
        float s2 = RED1[96 + lm] + RED1[128 + lm] + RED1[160 + lm];
        float mu = s * (1.0f/96.0f);
        float rstd = rsqrtf(s2*(1.0f/96.0f) - mu*mu + 1e-5f);
        #pragma unroll
        for(int q = 0; q < 4; ++q){
            int c = w*32 + 8*q + 4*hq;
            float4 gv = *(const float4*)(gf + c);
            float4 bv = *(const float4*)(btf + c);
            float ga[4] = {gv.x, gv.y, gv.z, gv.w};
            float ba[4] = {bv.x, bv.y, bv.z, bv.w};
            #pragma unroll
            for(int r = 0; r < 4; ++r)
                ZT[(c + r)*36 + lm] = (fv[4*q+r] - mu)*rstd*ga[r] + ba[r];
        }
    }
    __syncthreads();                                   // b10: ZT ready
    float* ob = out + (size_t)b*C*T + t0;
    for(int e = tid; e < 96*8; e += 192){
        int c = e >> 3, qq = e & 7;
        *(float4*)(ob + (size_t)c*T + qq*4) = *(const float4*)(ZT + c*36 + qq*4);
    }
}

extern "C" void kernel_launch(void* const* d_in, const int* in_sizes, int n_in,
                              void* d_out, int out_size, void* d_ws, size_t ws_size,
                              hipStream_t stream) {
    const float* x     = (const float*)d_in[0];
    const float* w_qkv = (const float*)d_in[1];
    const float* b_qkv = (const float*)d_in[2];
    const float* w_out = (const float*)d_in[3];
    const float* b_out = (const float*)d_in[4];
    const float* ln1_g = (const float*)d_in[5];
    const float* ln1_b = (const float*)d_in[6];
    const float* w_ff1 = (const float*)d_in[7];
    const float* b_ff1 = (const float*)d_in[8];
    const float* w_ff2 = (const float*)d_in[9];
    const float* b_ff2 = (const float*)d_in[10];
    const float* ln2_g = (const float*)d_in[11];
    const float* ln2_b = (const float*)d_in[12];
    const float* lnf_g = (const float*)d_in[13];
    const float* lnf_b = (const float*)d_in[14];
    float* out = (float*)d_out;

    // ws: only bf16 fragment-major weights (860 KB)
    bf16* wts = (bf16*)d_ws;
    bf16* wqs = wts;
    bf16* wos = wts + 27648;
    bf16* w1s = wts + 36864;
    bf16* w2s = wts + 233472;

    cvtw_kernel   <<<1680, 256, 0, stream>>>(w_qkv, w_out, w_ff1, w_ff2, wts);
    encoder_kernel<<<B*(T/32), 192, 0, stream>>>(x, wqs, wos, w1s, w2s,
                                                 b_qkv, b_out, ln1_g, ln1_b,
                                                 b_ff1, b_ff2, ln2_g, ln2_b,
                                                 lnf_g, lnf_b, out);
}